// Round 3
// baseline (7705.938 us; speedup 1.0000x reference)
//
#include <hip/hip_runtime.h>
#include <math.h>

#define BB 32
#define EE 512
#define VV 8192
#define TT 16
#define LL 4
#define FFD 2048
#define NHD 8
#define HDD 64
#define LDP 520
#define G 64
#define SCALE_EMB 22.627416997969522f

typedef __attribute__((ext_vector_type(8))) short bf16x8;
typedef __attribute__((ext_vector_type(4))) float f32x4;

__device__ __forceinline__ f32x4 mfma16(bf16x8 a, bf16x8 b, f32x4 c){
  return __builtin_amdgcn_mfma_f32_16x16x32_bf16(a, b, c, 0, 0, 0);
}

__device__ __forceinline__ float wave_sum(float v){
  for (int o = 32; o; o >>= 1) v += __shfl_down(v, o);
  return __shfl(v, 0);
}
__device__ __forceinline__ float wave_max(float v){
  for (int o = 32; o; o >>= 1) v = fmaxf(v, __shfl_down(v, o));
  return __shfl(v, 0);
}
__device__ __forceinline__ unsigned short f_to_bf(float f){
  unsigned u = __float_as_uint(f);
  unsigned r = (u + 0x7fffu + ((u >> 16) & 1u)) >> 16;
  return (unsigned short)r;
}

__device__ __forceinline__ void mmloop(int nks, const unsigned short* ar,
    const unsigned short* b0r, const unsigned short* b1r, f32x4& a0, f32x4& a1){
  #pragma unroll 4
  for (int ks = 0; ks < nks; ++ks){
    bf16x8 a  = *reinterpret_cast<const bf16x8*>(ar + ks*32);
    bf16x8 b0 = *reinterpret_cast<const bf16x8*>(b0r + ks*32);
    bf16x8 b1 = *reinterpret_cast<const bf16x8*>(b1r + ks*32);
    a0 = mfma16(a, b0, a0);
    a1 = mfma16(a, b1, a1);
  }
}

// Stage [B,E] into padded-LDS bf16; optional pending LN from ybuf; optional fp32 LN'd copy out.
__device__ __forceinline__ void stage_x(unsigned short* xs,
    const float* __restrict__ xraw, const float* __restrict__ ybuf,
    const float* __restrict__ g, const float* __restrict__ bt, int use_ln,
    float* __restrict__ xlnout){
  if (!use_ln){
    for (int i = threadIdx.x; i < BB*EE; i += 256){
      int r = i >> 9, c = i & 511;
      xs[r*LDP + c] = f_to_bf(xraw[i]);
    }
  } else {
    const int lane = threadIdx.x & 63, wv = threadIdx.x >> 6;
    for (int r = wv*8; r < wv*8 + 8; ++r){
      float vals[8]; float s = 0.f, s2 = 0.f;
      #pragma unroll
      for (int j = 0; j < 8; ++j){
        float v = ybuf[r*EE + lane + j*64];
        vals[j] = v; s += v; s2 += v*v;
      }
      s = wave_sum(s); s2 = wave_sum(s2);
      float m = s * (1.f/EE);
      float inv = rsqrtf(s2*(1.f/EE) - m*m + 1e-5f);
      #pragma unroll
      for (int j = 0; j < 8; ++j){
        int c = lane + j*64;
        float v = (vals[j]-m)*inv*g[c] + bt[c];
        xs[r*LDP + c] = f_to_bf(v);
        if (xlnout) xlnout[r*EE + c] = v;
      }
    }
  }
  __syncthreads();
}

struct MegaParams {
  const float *enc, *spec, *embw, *outwf, *outb, *gumb;
  const float *saqw, *saqb, *saow, *saob;
  const float *caqw, *caqb, *caow, *caob;
  const float *l1g, *l1b, *l2g, *l2b, *l3g, *l3b;
  const float *w1f, *b1, *w2f, *b2;
  float *dseq, *ddist;
  float *x, *y, *q, *xln, *o2, *logits, *venc, *cac, *kc, *vc;
  unsigned short *obf, *Hb, *sbf;
  unsigned short *wqkvb, *owb, *w1b, *w2b, *outwb, *eTb, *cavwb, *caowb;
  unsigned *cnt;
};

__global__ __launch_bounds__(256) void mega(MegaParams p){
  __shared__ unsigned short xs[BB*LDP];
  __shared__ float att[NHD*16];
  __shared__ float red[8];
  unsigned phase = 0;
  auto bar = [&](){
    ++phase;
    __syncthreads();
    if (threadIdx.x == 0){
      __hip_atomic_fetch_add(p.cnt, 1u, __ATOMIC_ACQ_REL, __HIP_MEMORY_SCOPE_AGENT);
      while (__hip_atomic_load(p.cnt, __ATOMIC_ACQUIRE, __HIP_MEMORY_SCOPE_AGENT) < phase*(unsigned)G)
        __builtin_amdgcn_s_sleep(1);
    }
    __syncthreads();
  };

  const int t = threadIdx.x, w = t >> 6, ln = t & 63;
  const int lm = ln & 15, kg = ln >> 4;

  // ---------------- stage 0: conversions, transposes, inits ----------------
  {
    const int tid = blockIdx.x*256 + t, stp = G*256;
    #define CVT(SRC, DST, N4) \
      for (int i = tid; i < (N4); i += stp){ \
        float4 v = ((const float4*)(SRC))[i]; \
        ushort4 o; o.x=f_to_bf(v.x); o.y=f_to_bf(v.y); o.z=f_to_bf(v.z); o.w=f_to_bf(v.w); \
        ((ushort4*)(DST))[i] = o; }
    CVT(p.saqw, p.wqkvb, LL*3*EE*EE/4)
    CVT(p.saow, p.owb,   LL*EE*EE/4)
    CVT(p.w1f,  p.w1b,   LL*FFD*EE/4)
    CVT(p.w2f,  p.w2b,   LL*FFD*EE/4)
    CVT(p.outwf,p.outwb, VV*EE/4)
    CVT(p.caow, p.caowb, LL*EE*EE/4)
    #undef CVT
    for (int i = tid; i < LL*EE*EE/4; i += stp){
      int l = i / (EE*EE/4), r = i - l*(EE*EE/4);
      float4 v = ((const float4*)p.caqw)[(size_t)l*(3*EE*EE/4) + 2*(EE*EE/4) + r];
      ushort4 o; o.x=f_to_bf(v.x); o.y=f_to_bf(v.y); o.z=f_to_bf(v.z); o.w=f_to_bf(v.w);
      ((ushort4*)p.cavwb)[i] = o;
    }
    for (int i = tid; i < BB*VV; i += stp){
      int b = i >> 13, v = i & (VV-1);
      p.dseq[(size_t)b*((TT+1)*VV) + (size_t)TT*VV + v] = (v == 0) ? 1.f : 0.f;
    }
    for (int i = tid; i < BB*EE; i += stp) p.x[i] = p.spec[i & (EE-1)];
    // embT transpose via LDS
    for (int t64 = blockIdx.x; t64 < (VV/64)*(EE/64); t64 += G){
      int vt = t64 >> 3, et = t64 & 7;
      __syncthreads();
      for (int i = t; i < 64*64; i += 256){
        int vv = i >> 6, ee = i & 63;
        xs[vv*68 + ee] = f_to_bf(p.embw[(size_t)(vt*64+vv)*EE + et*64 + ee]);
      }
      __syncthreads();
      for (int i = t; i < 64*64; i += 256){
        int ee = i >> 6, vv = i & 63;
        p.eTb[(size_t)(et*64+ee)*VV + vt*64 + vv] = xs[vv*68 + ee];
      }
    }
  }
  bar();

  // ---------------- venc[l] = enc @ cavw[l].T + cavb ----------------
  {
    __syncthreads();
    for (int i = t; i < BB*EE; i += 256){
      int r = i >> 9, c = i & 511;
      xs[r*LDP + c] = f_to_bf(p.enc[i]);
    }
    __syncthreads();
    for (int tile = blockIdx.x; tile < LL*8; tile += G){
      int l = tile >> 3, et = tile & 7;
      int f0w = et*64 + w*16;
      const unsigned short* ar = p.cavwb + (size_t)l*EE*EE + (size_t)(f0w+lm)*EE + kg*8;
      const unsigned short* b0r = xs + lm*LDP + kg*8;
      const unsigned short* b1r = xs + (lm+16)*LDP + kg*8;
      f32x4 a0 = {0.f,0.f,0.f,0.f}, a1 = {0.f,0.f,0.f,0.f};
      mmloop(16, ar, b0r, b1r, a0, a1);
      const float* bl = p.caqb + l*3*EE + 2*EE;
      #pragma unroll
      for (int r = 0; r < 4; ++r){
        int f = f0w + kg*4 + r;
        float bv = bl[f];
        p.venc[(size_t)l*BB*EE + lm*EE + f] = a0[r] + bv;
        p.venc[(size_t)l*BB*EE + (lm+16)*EE + f] = a1[r] + bv;
      }
    }
  }
  bar();

  // ---------------- cac[l] = venc[l] @ caow[l].T + caob ----------------
  for (int tile = blockIdx.x; tile < LL*8; tile += G){
    int l = tile >> 3, et = tile & 7;
    __syncthreads();
    for (int i = t; i < BB*EE; i += 256){
      int r = i >> 9, c = i & 511;
      xs[r*LDP + c] = f_to_bf(p.venc[(size_t)l*BB*EE + i]);
    }
    __syncthreads();
    int f0w = et*64 + w*16;
    const unsigned short* ar = p.caowb + (size_t)l*EE*EE + (size_t)(f0w+lm)*EE + kg*8;
    const unsigned short* b0r = xs + lm*LDP + kg*8;
    const unsigned short* b1r = xs + (lm+16)*LDP + kg*8;
    f32x4 a0 = {0.f,0.f,0.f,0.f}, a1 = {0.f,0.f,0.f,0.f};
    mmloop(16, ar, b0r, b1r, a0, a1);
    #pragma unroll
    for (int r = 0; r < 4; ++r){
      int f = f0w + kg*4 + r;
      float bv = p.caob[l*EE + f];
      p.cac[(size_t)l*BB*EE + lm*EE + f] = a0[r] + bv;
      p.cac[(size_t)l*BB*EE + (lm+16)*EE + f] = a1[r] + bv;
    }
  }
  bar();

  // ---------------- autoregressive steps ----------------
  for (int step = 0; step < TT; ++step){
    const int tpos = step, tlen = step + 1;
    for (int l = 0; l < LL; ++l){
      const int use_ln = (l > 0);
      const float* lg = p.l3g + (use_ln ? (l-1)*EE : 0);
      const float* lb = p.l3b + (use_ln ? (l-1)*EE : 0);
      float* kcl = p.kc + (size_t)l*BB*EE*TT;
      float* vcl = p.vc + (size_t)l*BB*EE*TT;
      const unsigned short* Wq = p.wqkvb + (size_t)l*3*EE*EE;
      const float* bq = p.saqb + l*3*EE;

      // ---- qkv ----
      {
        float* xlo = (use_ln && blockIdx.x == 0) ? p.xln : nullptr;
        stage_x(xs, p.x, p.y, lg, lb, use_ln, xlo);
        for (int tile = blockIdx.x; tile < 24; tile += G){
          int f0w = tile*64 + w*16;
          const unsigned short* ar = Wq + (size_t)(f0w+lm)*EE + kg*8;
          const unsigned short* b0r = xs + lm*LDP + kg*8;
          const unsigned short* b1r = xs + (lm+16)*LDP + kg*8;
          f32x4 a0 = {0.f,0.f,0.f,0.f}, a1 = {0.f,0.f,0.f,0.f};
          mmloop(16, ar, b0r, b1r, a0, a1);
          #pragma unroll
          for (int r = 0; r < 4; ++r){
            int f = f0w + kg*4 + r;
            float bv = bq[f];
            float v0 = a0[r] + bv, v1 = a1[r] + bv;
            if (f < EE){
              p.q[lm*EE + f] = v0;
              p.q[(lm+16)*EE + f] = v1;
            } else if (f < 2*EE){
              int ff = f - EE, h = ff >> 6, d = ff & 63;
              kcl[((size_t)(lm*NHD + h)*TT + tpos)*HDD + d] = v0;
              kcl[((size_t)((lm+16)*NHD + h)*TT + tpos)*HDD + d] = v1;
            } else {
              int ff = f - 2*EE, h = ff >> 6, d = ff & 63;
              vcl[((size_t)(lm*NHD + h)*TT + tpos)*HDD + d] = v0;
              vcl[((size_t)((lm+16)*NHD + h)*TT + tpos)*HDD + d] = v1;
            }
          }
        }
      }
      bar();

      // ---- attention core ----
      for (int tile = blockIdx.x; tile < 32; tile += G){
        const int b = tile;
        #pragma unroll
        for (int hh = 0; hh < 2; ++hh){
          const int h = w*2 + hh;
          const float* kh = kcl + (size_t)(b*NHD + h)*TT*HDD;
          const float* vh = vcl + (size_t)(b*NHD + h)*TT*HDD;
          const float* qh = p.q + b*EE + h*HDD;
          float sc = -1e30f;
          if (ln < tlen){
            float a = 0.f;
            for (int d = 0; d < HDD; d += 4){
              float4 qv = *(const float4*)(qh + d);
              float4 kv = *(const float4*)(kh + ln*HDD + d);
              a += qv.x*kv.x + qv.y*kv.y + qv.z*kv.z + qv.w*kv.w;
            }
            sc = a*0.125f;
          }
          float m = wave_max(sc);
          float e = (ln < tlen) ? __expf(sc - m) : 0.f;
          float s = wave_sum(e);
          if (ln < 16) att[h*16 + ln] = e / s;
          float o = 0.f;
          for (int j = 0; j < tlen; ++j) o += att[h*16 + j] * vh[j*HDD + ln];
          p.obf[b*EE + h*HDD + ln] = f_to_bf(o);
        }
      }
      bar();

      // ---- out-projection + residual ----
      {
        const float* resid = use_ln ? p.xln : p.x;
        const unsigned short* Wo = p.owb + (size_t)l*EE*EE;
        for (int tile = blockIdx.x; tile < 8; tile += G){
          int f0w = tile*64 + w*16;
          const unsigned short* ar = Wo + (size_t)(f0w+lm)*EE + kg*8;
          const unsigned short* b0r = p.obf + lm*EE + kg*8;
          const unsigned short* b1r = p.obf + (lm+16)*EE + kg*8;
          f32x4 a0 = {0.f,0.f,0.f,0.f}, a1 = {0.f,0.f,0.f,0.f};
          mmloop(16, ar, b0r, b1r, a0, a1);
          #pragma unroll
          for (int r = 0; r < 4; ++r){
            int f = f0w + kg*4 + r;
            float bv = p.saob[l*EE + f];
            p.o2[lm*EE + f]      = a0[r] + bv + resid[lm*EE + f];
            p.o2[(lm+16)*EE + f] = a1[r] + bv + resid[(lm+16)*EE + f];
          }
        }
      }
      bar();

      // ---- ffn1: LN1 + ca + LN2 prologue, then gelu GEMM ----
      {
        const float* g1 = p.l1g + l*EE; const float* b1g = p.l1b + l*EE;
        const float* g2 = p.l2g + l*EE; const float* b2g = p.l2b + l*EE;
        const float* cacl = p.cac + (size_t)l*BB*EE;
        const float* b2bias = p.b2 + l*EE;
        float* yi = (blockIdx.x == 0) ? p.y : nullptr;
        const int lane = ln, wv = w;
        for (int r = wv*8; r < wv*8 + 8; ++r){
          float vals[8]; float s = 0.f, s2 = 0.f;
          #pragma unroll
          for (int j = 0; j < 8; ++j){
            float v = p.o2[r*EE + lane + j*64];
            vals[j] = v; s += v; s2 += v*v;
          }
          s = wave_sum(s); s2 = wave_sum(s2);
          float m = s*(1.f/EE), inv = rsqrtf(s2*(1.f/EE) - m*m + 1e-5f);
          float nv[8]; float u = 0.f, u2 = 0.f;
          #pragma unroll
          for (int j = 0; j < 8; ++j){
            int c = lane + j*64;
            float v = (vals[j]-m)*inv*g1[c] + b1g[c] + cacl[r*EE + c];
            nv[j] = v; u += v; u2 += v*v;
          }
          u = wave_sum(u); u2 = wave_sum(u2);
          float m2 = u*(1.f/EE), inv2 = rsqrtf(u2*(1.f/EE) - m2*m2 + 1e-5f);
          #pragma unroll
          for (int j = 0; j < 8; ++j){
            int c = lane + j*64;
            float v = (nv[j]-m2)*inv2*g2[c] + b2g[c];
            xs[r*LDP + c] = f_to_bf(v);
            if (yi) yi[r*EE + c] = v + b2bias[c];
          }
        }
        __syncthreads();
        const unsigned short* W1 = p.w1b + (size_t)l*FFD*EE;
        const float* bb1 = p.b1 + l*FFD;
        for (int tile = blockIdx.x; tile < 32; tile += G){
          int f0w = tile*64 + w*16;
          const unsigned short* ar = W1 + (size_t)(f0w+lm)*EE + kg*8;
          const unsigned short* b0r = xs + lm*LDP + kg*8;
          const unsigned short* b1r = xs + (lm+16)*LDP + kg*8;
          f32x4 a0 = {0.f,0.f,0.f,0.f}, a1 = {0.f,0.f,0.f,0.f};
          mmloop(16, ar, b0r, b1r, a0, a1);
          #pragma unroll
          for (int r = 0; r < 4; ++r){
            int f = f0w + kg*4 + r;
            float bv = bb1[f];
            float v0 = a0[r] + bv, v1 = a1[r] + bv;
            v0 = 0.5f*v0*(1.f + erff(v0*0.70710678118654752f));
            v1 = 0.5f*v1*(1.f + erff(v1*0.70710678118654752f));
            p.Hb[lm*FFD + f] = f_to_bf(v0);
            p.Hb[(lm+16)*FFD + f] = f_to_bf(v1);
          }
        }
      }
      bar();

      // ---- ffn2: k-split atomics into y ----
      {
        const unsigned short* W2 = p.w2b + (size_t)l*EE*FFD;
        for (int tile = blockIdx.x; tile < 32; tile += G){
          int f0w = (tile & 7)*64 + w*16;
          int k0 = (tile >> 3)*512;
          const unsigned short* ar = W2 + (size_t)(f0w+lm)*FFD + k0 + kg*8;
          const unsigned short* b0r = p.Hb + lm*FFD + k0 + kg*8;
          const unsigned short* b1r = p.Hb + (lm+16)*FFD + k0 + kg*8;
          f32x4 a0 = {0.f,0.f,0.f,0.f}, a1 = {0.f,0.f,0.f,0.f};
          mmloop(16, ar, b0r, b1r, a0, a1);
          #pragma unroll
          for (int r = 0; r < 4; ++r){
            int f = f0w + kg*4 + r;
            atomicAdd(&p.y[lm*EE + f], a0[r]);
            atomicAdd(&p.y[(lm+16)*EE + f], a1[r]);
          }
        }
      }
      bar();
    }

    // ---- logits = LN3(y) @ outw.T + outb ----
    {
      stage_x(xs, nullptr, p.y, p.l3g + 3*EE, p.l3b + 3*EE, 1, nullptr);
      for (int tile = blockIdx.x; tile < 128; tile += G){
        int f0w = tile*64 + w*16;
        const unsigned short* ar = p.outwb + (size_t)(f0w+lm)*EE + kg*8;
        const unsigned short* b0r = xs + lm*LDP + kg*8;
        const unsigned short* b1r = xs + (lm+16)*LDP + kg*8;
        f32x4 a0 = {0.f,0.f,0.f,0.f}, a1 = {0.f,0.f,0.f,0.f};
        mmloop(16, ar, b0r, b1r, a0, a1);
        #pragma unroll
        for (int r = 0; r < 4; ++r){
          int f = f0w + kg*4 + r;
          float bv = p.outb[f];
          p.logits[lm*VV + f]      = a0[r] + bv;
          p.logits[(lm+16)*VV + f] = a1[r] + bv;
        }
      }
    }
    bar();

    // ---- dual softmax + sample; zero x ----
    {
      const float* gstep = p.gumb + (size_t)step*BB*VV;
      for (int tile = blockIdx.x; tile < 32; tile += G){
        const int b = tile;
        const float* lr = p.logits + (size_t)b*VV;
        const float* gr = gstep + (size_t)b*VV;
        float m1 = -1e30f, m2 = -1e30f;
        for (int i = t; i < VV; i += 256){
          float lv = lr[i];
          m1 = fmaxf(m1, lv);
          m2 = fmaxf(m2, lv + gr[i]);
        }
        for (int o = 32; o; o >>= 1){ m1 = fmaxf(m1, __shfl_down(m1,o)); m2 = fmaxf(m2, __shfl_down(m2,o)); }
        if (ln == 0){ red[w] = m1; red[4+w] = m2; }
        __syncthreads();
        m1 = fmaxf(fmaxf(red[0],red[1]), fmaxf(red[2],red[3]));
        m2 = fmaxf(fmaxf(red[4],red[5]), fmaxf(red[6],red[7]));
        __syncthreads();
        float s1 = 0.f, s2 = 0.f;
        for (int i = t; i < VV; i += 256){
          float lv = lr[i];
          s1 += __expf(lv - m1);
          s2 += __expf(lv + gr[i] - m2);
        }
        for (int o = 32; o; o >>= 1){ s1 += __shfl_down(s1,o); s2 += __shfl_down(s2,o); }
        if (ln == 0){ red[w] = s1; red[4+w] = s2; }
        __syncthreads();
        s1 = red[0]+red[1]+red[2]+red[3];
        s2 = red[4]+red[5]+red[6]+red[7];
        float r1 = 1.f/s1, r2 = 1.f/s2;
        float* dq = p.dseq + (size_t)b*((TT+1)*VV) + (size_t)step*VV;
        float* dd = p.ddist + (size_t)step*BB*VV + (size_t)b*VV;
        for (int i = t; i < VV; i += 256){
          float lv = lr[i];
          dd[i] = __expf(lv - m1)*r1;
          float qv = __expf(lv + gr[i] - m2)*r2;
          dq[i] = qv;
          p.sbf[(size_t)b*VV + i] = f_to_bf(qv);
        }
        for (int i = t; i < EE; i += 256) p.x[b*EE + i] = 0.f;
        __syncthreads();
      }
    }
    bar();

    // ---- x += (sample @ emb) * sqrt(E) ----
    for (int tile = blockIdx.x; tile < 64; tile += G){
      int e0w = (tile & 7)*64 + w*16;
      int v0 = (tile >> 3)*1024;
      const unsigned short* ar  = p.eTb + (size_t)(e0w+lm)*VV + v0 + kg*8;
      const unsigned short* b0r = p.sbf + (size_t)lm*VV + v0 + kg*8;
      const unsigned short* b1r = p.sbf + (size_t)(lm+16)*VV + v0 + kg*8;
      f32x4 a0 = {0.f,0.f,0.f,0.f}, a1 = {0.f,0.f,0.f,0.f};
      mmloop(32, ar, b0r, b1r, a0, a1);
      #pragma unroll
      for (int r = 0; r < 4; ++r){
        int e = e0w + kg*4 + r;
        atomicAdd(&p.x[lm*EE + e], a0[r]*SCALE_EMB);
        atomicAdd(&p.x[(lm+16)*EE + e], a1[r]*SCALE_EMB);
      }
    }
    bar();
  }
}

// ---------------- host ----------------
extern "C" void kernel_launch(void* const* d_in, const int* in_sizes, int n_in,
                              void* d_out, int out_size, void* d_ws, size_t ws_size,
                              hipStream_t stream){
  (void)in_sizes; (void)n_in; (void)out_size; (void)ws_size;
  MegaParams p;
  p.enc  = (const float*)d_in[0];
  p.spec = (const float*)d_in[1];
  p.embw = (const float*)d_in[2];
  p.outwf= (const float*)d_in[3];
  p.outb = (const float*)d_in[4];
  p.gumb = (const float*)d_in[5];
  p.saqw = (const float*)d_in[6];
  p.saqb = (const float*)d_in[7];
  p.saow = (const float*)d_in[8];
  p.saob = (const float*)d_in[9];
  p.caqw = (const float*)d_in[10];
  p.caqb = (const float*)d_in[11];
  p.caow = (const float*)d_in[12];
  p.caob = (const float*)d_in[13];
  p.l1g  = (const float*)d_in[14];
  p.l1b  = (const float*)d_in[15];
  p.l2g  = (const float*)d_in[16];
  p.l2b  = (const float*)d_in[17];
  p.l3g  = (const float*)d_in[18];
  p.l3b  = (const float*)d_in[19];
  p.w1f  = (const float*)d_in[20];
  p.b1   = (const float*)d_in[21];
  p.w2f  = (const float*)d_in[22];
  p.b2   = (const float*)d_in[23];

  float* dout = (float*)d_out;
  p.dseq  = dout;
  p.ddist = dout + (size_t)BB*(TT+1)*VV;

  unsigned char* wp = (unsigned char*)d_ws;
  auto alloc = [&](size_t bytes) -> void* {
    void* r = (void*)wp; wp += (bytes + 255) & ~(size_t)255; return r;
  };
  p.x      = (float*)alloc(BB*EE*4);
  p.y      = (float*)alloc(BB*EE*4);
  p.q      = (float*)alloc(BB*EE*4);
  p.xln    = (float*)alloc(BB*EE*4);
  p.o2     = (float*)alloc(BB*EE*4);
  p.logits = (float*)alloc((size_t)BB*VV*4);
  p.venc   = (float*)alloc((size_t)LL*BB*EE*4);
  p.cac    = (float*)alloc((size_t)LL*BB*EE*4);
  p.kc     = (float*)alloc((size_t)LL*BB*EE*TT*4);
  p.vc     = (float*)alloc((size_t)LL*BB*EE*TT*4);
  p.obf    = (unsigned short*)alloc(BB*EE*2);
  p.Hb     = (unsigned short*)alloc(BB*FFD*2);
  p.sbf    = (unsigned short*)alloc((size_t)BB*VV*2);
  p.wqkvb  = (unsigned short*)alloc((size_t)LL*3*EE*EE*2);
  p.owb    = (unsigned short*)alloc((size_t)LL*EE*EE*2);
  p.w1b    = (unsigned short*)alloc((size_t)LL*FFD*EE*2);
  p.w2b    = (unsigned short*)alloc((size_t)LL*FFD*EE*2);
  p.outwb  = (unsigned short*)alloc((size_t)VV*EE*2);
  p.eTb    = (unsigned short*)alloc((size_t)EE*VV*2);
  p.cavwb  = (unsigned short*)alloc((size_t)LL*EE*EE*2);
  p.caowb  = (unsigned short*)alloc((size_t)LL*EE*EE*2);
  p.cnt    = (unsigned*)alloc(256);

  hipMemsetAsync((void*)p.cnt, 0, 256, stream);
  mega<<<dim3(G), dim3(256), 0, stream>>>(p);
}

// Round 4
// 5656.335 us; speedup vs baseline: 1.3624x; 1.3624x over previous
//
#include <hip/hip_runtime.h>
#include <math.h>

#define BB 32
#define EE 512
#define VV 8192
#define TT 16
#define LL 4
#define FFD 2048
#define NHD 8
#define HDD 64
#define LDP 520
#define G 64
#define NW 8
#define BLK 512
#define SCALE_EMB 22.627416997969522f

typedef __attribute__((ext_vector_type(8))) short bf16x8;
typedef __attribute__((ext_vector_type(4))) float f32x4;

union BF8 { bf16x8 v; unsigned u[4]; unsigned long long q[2]; };

__device__ __forceinline__ f32x4 mfma16(bf16x8 a, bf16x8 b, f32x4 c){
  return __builtin_amdgcn_mfma_f32_16x16x32_bf16(a, b, c, 0, 0, 0);
}
__device__ __forceinline__ float wave_sum(float v){
  for (int o = 32; o; o >>= 1) v += __shfl_down(v, o);
  return __shfl(v, 0);
}
__device__ __forceinline__ unsigned short f_to_bf(float f){
  unsigned u = __float_as_uint(f);
  return (unsigned short)((u + 0x7fffu + ((u >> 16) & 1u)) >> 16);
}
__device__ __forceinline__ unsigned pk2(float a, float b){
  return (unsigned)f_to_bf(a) | ((unsigned)f_to_bf(b) << 16);
}
// ---- sc1 (device-coherent) 8B access helpers: relaxed agent-scope atomics ----
__device__ __forceinline__ float2 ld8(const float* p){
  unsigned long long u = __hip_atomic_load((const unsigned long long*)p,
      __ATOMIC_RELAXED, __HIP_MEMORY_SCOPE_AGENT);
  float2 r; r.x = __uint_as_float((unsigned)u); r.y = __uint_as_float((unsigned)(u >> 32));
  return r;
}
__device__ __forceinline__ void st8(float* p, float a, float b){
  unsigned long long u = (unsigned long long)__float_as_uint(a) |
                         ((unsigned long long)__float_as_uint(b) << 32);
  __hip_atomic_store((unsigned long long*)p, u, __ATOMIC_RELAXED, __HIP_MEMORY_SCOPE_AGENT);
}
__device__ __forceinline__ void st4(float* p, float a){
  __hip_atomic_store(p, a, __ATOMIC_RELAXED, __HIP_MEMORY_SCOPE_AGENT);
}
__device__ __forceinline__ unsigned long long ld8u(const unsigned short* p){
  return __hip_atomic_load((const unsigned long long*)p,
      __ATOMIC_RELAXED, __HIP_MEMORY_SCOPE_AGENT);
}
__device__ __forceinline__ void st8u(unsigned short* p, unsigned lo, unsigned hi){
  unsigned long long u = (unsigned long long)lo | ((unsigned long long)hi << 32);
  __hip_atomic_store((unsigned long long*)p, u, __ATOMIC_RELAXED, __HIP_MEMORY_SCOPE_AGENT);
}

__device__ __forceinline__ void mmloop(int nks, const unsigned short* ar,
    const unsigned short* b0r, const unsigned short* b1r, f32x4& a0, f32x4& a1){
  #pragma unroll 4
  for (int ks = 0; ks < nks; ++ks){
    bf16x8 a  = *reinterpret_cast<const bf16x8*>(ar + ks*32);
    bf16x8 b0 = *reinterpret_cast<const bf16x8*>(b0r + ks*32);
    bf16x8 b1 = *reinterpret_cast<const bf16x8*>(b1r + ks*32);
    a0 = mfma16(a, b0, a0);
    a1 = mfma16(a, b1, a1);
  }
}

// ---------------- prep kernel: weight conversion + transposes + inits ----------------
struct PrepParams {
  const float *spec, *embw, *outwf, *saqw, *saow, *caqw, *caow, *w1f, *w2f;
  float *dseq, *x;
  unsigned short *wqkvb, *owb, *w1b, *w2b, *outwb, *cavwb, *caowb, *eTb;
};

__global__ __launch_bounds__(256) void k_prep(PrepParams p){
  __shared__ unsigned short tl[64*68];
  const int tid = blockIdx.x*256 + threadIdx.x, stp = gridDim.x*256;
  #define CVT(SRC, DST, N4) \
    for (int i = tid; i < (N4); i += stp){ \
      float4 v = ((const float4*)(SRC))[i]; \
      ushort4 o; o.x=f_to_bf(v.x); o.y=f_to_bf(v.y); o.z=f_to_bf(v.z); o.w=f_to_bf(v.w); \
      ((ushort4*)(DST))[i] = o; }
  CVT(p.saqw, p.wqkvb, LL*3*EE*EE/4)
  CVT(p.saow, p.owb,   LL*EE*EE/4)
  CVT(p.w1f,  p.w1b,   LL*FFD*EE/4)
  CVT(p.w2f,  p.w2b,   LL*FFD*EE/4)
  CVT(p.outwf,p.outwb, VV*EE/4)
  CVT(p.caow, p.caowb, LL*EE*EE/4)
  #undef CVT
  for (int i = tid; i < LL*EE*EE/4; i += stp){
    int l = i / (EE*EE/4), r = i - l*(EE*EE/4);
    float4 v = ((const float4*)p.caqw)[(size_t)l*(3*EE*EE/4) + 2*(EE*EE/4) + r];
    ushort4 o; o.x=f_to_bf(v.x); o.y=f_to_bf(v.y); o.z=f_to_bf(v.z); o.w=f_to_bf(v.w);
    ((ushort4*)p.cavwb)[i] = o;
  }
  for (int i = tid; i < BB*VV; i += stp){
    int b = i >> 13, v = i & (VV-1);
    p.dseq[(size_t)b*((TT+1)*VV) + (size_t)TT*VV + v] = (v == 0) ? 1.f : 0.f;
  }
  for (int i = tid; i < BB*EE; i += stp) p.x[i] = p.spec[i & (EE-1)];
  // embT transpose: eT[e][v] = bf16(emb[v][e])
  for (int t64 = blockIdx.x; t64 < (VV/64)*(EE/64); t64 += gridDim.x){
    int vt = t64 >> 3, et = t64 & 7;
    __syncthreads();
    for (int i = threadIdx.x; i < 64*64; i += 256){
      int vv = i >> 6, ee = i & 63;
      tl[vv*68 + ee] = f_to_bf(p.embw[(size_t)(vt*64+vv)*EE + et*64 + ee]);
    }
    __syncthreads();
    for (int i = threadIdx.x; i < 64*16; i += 256){
      int ee = i >> 4, v4 = (i & 15)*4;
      ushort4 o;
      o.x = tl[(v4+0)*68 + ee]; o.y = tl[(v4+1)*68 + ee];
      o.z = tl[(v4+2)*68 + ee]; o.w = tl[(v4+3)*68 + ee];
      *(ushort4*)(p.eTb + (size_t)(et*64+ee)*VV + vt*64 + v4) = o;
    }
  }
}

// ---------------- mega kernel ----------------
struct MegaParams {
  const float *enc, *gumb, *outb;
  const float *saqb, *saob, *caqb, *caob;
  const float *l1g, *l1b, *l2g, *l2b, *l3g, *l3b, *b1, *b2;
  float *dseq, *ddist;
  float *x, *y, *q, *xln, *o2, *of, *logits, *venc, *cac, *kc, *vc;
  unsigned short *Hb, *sbf;
  const unsigned short *wqkvb, *owb, *w1b, *w2b, *outwb, *eTb, *cavwb, *caowb;
  unsigned *cnt;
};

// stage [B,E] into padded-LDS bf16 (sc1 source); optional pending LN; optional LN'd copy
__device__ __forceinline__ void stage_x(unsigned short* xs,
    const float* xraw, const float* ybuf,
    const float* g, const float* bt, int use_ln, float* xlnout){
  const int ln = threadIdx.x & 63, w = threadIdx.x >> 6;
  const int c0 = ln*8;
  #pragma unroll 1
  for (int r = w*4; r < w*4 + 4; ++r){
    float v[8];
    const float* src = (use_ln ? ybuf : xraw) + r*EE + c0;
    #pragma unroll
    for (int j = 0; j < 4; ++j){ float2 t2 = ld8(src + 2*j); v[2*j] = t2.x; v[2*j+1] = t2.y; }
    if (use_ln){
      float s = 0.f, s2 = 0.f;
      #pragma unroll
      for (int j = 0; j < 8; ++j){ s += v[j]; s2 += v[j]*v[j]; }
      s = wave_sum(s); s2 = wave_sum(s2);
      float m = s*(1.f/EE), inv = rsqrtf(s2*(1.f/EE) - m*m + 1e-5f);
      #pragma unroll
      for (int j = 0; j < 8; ++j) v[j] = (v[j]-m)*inv*g[c0+j] + bt[c0+j];
      if (xlnout){
        #pragma unroll
        for (int j = 0; j < 4; ++j) st8(xlnout + r*EE + c0 + 2*j, v[2*j], v[2*j+1]);
      }
    }
    uint4 pk;
    pk.x = pk2(v[0],v[1]); pk.y = pk2(v[2],v[3]); pk.z = pk2(v[4],v[5]); pk.w = pk2(v[6],v[7]);
    *(uint4*)(xs + r*LDP + c0) = pk;
  }
  __syncthreads();
}

__global__ __launch_bounds__(512, 2) void mega(MegaParams p){
  __shared__ unsigned short xs[BB*LDP];
  __shared__ float red[16];
  unsigned phase = 0;
  const int t = threadIdx.x, w = t >> 6, ln = t & 63;
  const int lm = ln & 15, kg = ln >> 4;
  auto bar = [&](){
    ++phase;
    __syncthreads();
    if (t == 0){
      __hip_atomic_fetch_add(p.cnt, 1u, __ATOMIC_RELEASE, __HIP_MEMORY_SCOPE_AGENT);
      while (__hip_atomic_load(p.cnt, __ATOMIC_RELAXED, __HIP_MEMORY_SCOPE_AGENT) < phase*(unsigned)G)
        __builtin_amdgcn_s_sleep(2);
    }
    __syncthreads();
  };

  // ---- stage A: venc[l] = enc @ cavw[l].T + bias ----
  {
    for (int i = t; i < BB*EE/4; i += BLK){
      int r = i >> 7, c = (i & 127)*4;
      float4 v = ((const float4*)p.enc)[i];
      uint2 pv; pv.x = pk2(v.x, v.y); pv.y = pk2(v.z, v.w);
      *(uint2*)(xs + r*LDP + c) = pv;
    }
    __syncthreads();
    for (int u = w*G + blockIdx.x; u < 128; u += NW*G){
      int l = u >> 5, rem = u & 31;
      int f0w = (rem >> 2)*64 + (rem & 3)*16;
      const unsigned short* ar = p.cavwb + (size_t)l*EE*EE + (size_t)(f0w+lm)*EE + kg*8;
      f32x4 a0 = {0,0,0,0}, a1 = {0,0,0,0};
      mmloop(16, ar, xs + lm*LDP + kg*8, xs + (lm+16)*LDP + kg*8, a0, a1);
      int f = f0w + kg*4;
      const float* bl = p.caqb + l*3*EE + 2*EE;
      float* vb = p.venc + (size_t)l*BB*EE;
      st8(vb + lm*EE + f,        a0[0]+bl[f],   a0[1]+bl[f+1]);
      st8(vb + lm*EE + f + 2,    a0[2]+bl[f+2], a0[3]+bl[f+3]);
      st8(vb + (lm+16)*EE + f,   a1[0]+bl[f],   a1[1]+bl[f+1]);
      st8(vb + (lm+16)*EE + f+2, a1[2]+bl[f+2], a1[3]+bl[f+3]);
    }
  }
  bar();

  // ---- stage B: cac[l] = venc[l] @ caow[l].T + bias ----
  if (blockIdx.x < 32){
    int l = blockIdx.x >> 3, et = blockIdx.x & 7;
    const float* vb = p.venc + (size_t)l*BB*EE;
    for (int i = t; i < BB*EE/2; i += BLK){
      int r = i >> 8, c = (i & 255)*2;
      float2 v = ld8(vb + 2*i);
      *(unsigned*)(xs + r*LDP + c) = pk2(v.x, v.y);
    }
    __syncthreads();
    if (w < 4){
      int f0w = et*64 + w*16;
      const unsigned short* ar = p.caowb + (size_t)l*EE*EE + (size_t)(f0w+lm)*EE + kg*8;
      f32x4 a0 = {0,0,0,0}, a1 = {0,0,0,0};
      mmloop(16, ar, xs + lm*LDP + kg*8, xs + (lm+16)*LDP + kg*8, a0, a1);
      int f = f0w + kg*4;
      const float* bl = p.caob + l*EE;
      float* cb = p.cac + (size_t)l*BB*EE;
      st8(cb + lm*EE + f,        a0[0]+bl[f],   a0[1]+bl[f+1]);
      st8(cb + lm*EE + f + 2,    a0[2]+bl[f+2], a0[3]+bl[f+3]);
      st8(cb + (lm+16)*EE + f,   a1[0]+bl[f],   a1[1]+bl[f+1]);
      st8(cb + (lm+16)*EE + f+2, a1[2]+bl[f+2], a1[3]+bl[f+3]);
    }
  }
  bar();

  // ---------------- autoregressive steps ----------------
  for (int step = 0; step < TT; ++step){
    const int tpos = step, tlen = step + 1;
    for (int l = 0; l < LL; ++l){
      const int use_ln = (l > 0);
      const float* lg = p.l3g + (use_ln ? (l-1)*EE : 0);
      const float* lb = p.l3b + (use_ln ? (l-1)*EE : 0);
      float* kcl = p.kc + (size_t)l*BB*EE*TT;
      float* vcl = p.vc + (size_t)l*BB*EE*TT;

      // ---- qkv ----
      {
        stage_x(xs, p.x, p.y, lg, lb, use_ln,
                (use_ln && blockIdx.x == 0) ? p.xln : nullptr);
        const unsigned short* Wq = p.wqkvb + (size_t)l*3*EE*EE;
        const float* bq = p.saqb + l*3*EE;
        for (int u = w*G + blockIdx.x; u < 96; u += NW*G){
          int f0w = (u >> 2)*64 + (u & 3)*16;
          const unsigned short* ar = Wq + (size_t)(f0w+lm)*EE + kg*8;
          f32x4 a0 = {0,0,0,0}, a1 = {0,0,0,0};
          mmloop(16, ar, xs + lm*LDP + kg*8, xs + (lm+16)*LDP + kg*8, a0, a1);
          int f = f0w + kg*4;
          float r00=a0[0]+bq[f], r01=a0[1]+bq[f+1], r02=a0[2]+bq[f+2], r03=a0[3]+bq[f+3];
          float r10=a1[0]+bq[f], r11=a1[1]+bq[f+1], r12=a1[2]+bq[f+2], r13=a1[3]+bq[f+3];
          if (f < EE){
            st8(&p.q[lm*EE+f], r00, r01);      st8(&p.q[lm*EE+f+2], r02, r03);
            st8(&p.q[(lm+16)*EE+f], r10, r11); st8(&p.q[(lm+16)*EE+f+2], r12, r13);
          } else if (f < 2*EE){
            int ff = f - EE, h = ff >> 6, d = ff & 63;
            float* k0p = kcl + ((size_t)(lm*NHD+h)*TT + tpos)*HDD + d;
            float* k1p = kcl + ((size_t)((lm+16)*NHD+h)*TT + tpos)*HDD + d;
            st8(k0p, r00, r01); st8(k0p+2, r02, r03);
            st8(k1p, r10, r11); st8(k1p+2, r12, r13);
          } else {
            int ff = f - 2*EE, h = ff >> 6, d = ff & 63;
            float* v0p = vcl + ((size_t)(lm*NHD+h)*TT + tpos)*HDD + d;
            float* v1p = vcl + ((size_t)((lm+16)*NHD+h)*TT + tpos)*HDD + d;
            st8(v0p, r00, r01); st8(v0p+2, r02, r03);
            st8(v1p, r10, r11); st8(v1p+2, r12, r13);
          }
        }
      }
      bar();

      // ---- attention core (KV cache positions are write-once: normal cached reads) ----
      for (int u = w*G + blockIdx.x; u < 128; u += NW*G){
        int b = u >> 2, hp = u & 3;
        #pragma unroll
        for (int hh = 0; hh < 2; ++hh){
          int h = hp*2 + hh;
          const float* kh = kcl + (size_t)(b*NHD + h)*TT*HDD;
          const float* vh = vcl + (size_t)(b*NHD + h)*TT*HDD;
          const float* qh = p.q + b*EE + h*HDD;
          float sc = -1e30f;
          if (ln < tlen){
            float a = 0.f;
            for (int d = 0; d < HDD; d += 4){
              float2 q0 = ld8(qh + d), q1 = ld8(qh + d + 2);
              float4 kv = *(const float4*)(kh + ln*HDD + d);
              a += q0.x*kv.x + q0.y*kv.y + q1.x*kv.z + q1.y*kv.w;
            }
            sc = a*0.125f;
          }
          float m = sc;
          for (int o = 32; o; o >>= 1) m = fmaxf(m, __shfl_down(m, o));
          m = __shfl(m, 0);
          float e = (ln < tlen) ? __expf(sc - m) : 0.f;
          float s = wave_sum(e);
          float pr = e / s;
          float o = 0.f;
          for (int j = 0; j < tlen; ++j) o += __shfl(pr, j) * vh[j*HDD + ln];
          st4(&p.of[b*EE + h*HDD + ln], o);
        }
      }
      bar();

      // ---- out-projection + bias + residual ----
      {
        const float* resid = use_ln ? p.xln : p.x;
        const unsigned short* Wo = p.owb + (size_t)l*EE*EE;
        const float* ob = p.saob + l*EE;
        for (int u = w*G + blockIdx.x; u < 32; u += NW*G){
          int f0w = (u >> 2)*64 + (u & 3)*16;
          const unsigned short* ar = Wo + (size_t)(f0w+lm)*EE + kg*8;
          f32x4 a0 = {0,0,0,0}, a1 = {0,0,0,0};
          #pragma unroll 2
          for (int ks = 0; ks < 16; ++ks){
            bf16x8 af = *reinterpret_cast<const bf16x8*>(ar + ks*32);
            const float* s0 = p.of + lm*EE + ks*32 + kg*8;
            const float* s1 = p.of + (lm+16)*EE + ks*32 + kg*8;
            BF8 b0, b1;
            #pragma unroll
            for (int j = 0; j < 4; ++j){
              float2 u0 = ld8(s0 + 2*j); b0.u[j] = pk2(u0.x, u0.y);
              float2 u1 = ld8(s1 + 2*j); b1.u[j] = pk2(u1.x, u1.y);
            }
            a0 = mfma16(af, b0.v, a0);
            a1 = mfma16(af, b1.v, a1);
          }
          int f = f0w + kg*4;
          float2 r0a = ld8(resid + lm*EE + f),      r0b = ld8(resid + lm*EE + f + 2);
          float2 r1a = ld8(resid + (lm+16)*EE + f), r1b = ld8(resid + (lm+16)*EE + f + 2);
          st8(&p.o2[lm*EE+f],        a0[0]+ob[f]+r0a.x,   a0[1]+ob[f+1]+r0a.y);
          st8(&p.o2[lm*EE+f+2],      a0[2]+ob[f+2]+r0b.x, a0[3]+ob[f+3]+r0b.y);
          st8(&p.o2[(lm+16)*EE+f],   a1[0]+ob[f]+r1a.x,   a1[1]+ob[f+1]+r1a.y);
          st8(&p.o2[(lm+16)*EE+f+2], a1[2]+ob[f+2]+r1b.x, a1[3]+ob[f+3]+r1b.y);
        }
      }
      bar();

      // ---- ffn1: LN1 + ca + LN2 prologue, gelu GEMM ----
      {
        const float* g1 = p.l1g + l*EE; const float* b1g = p.l1b + l*EE;
        const float* g2 = p.l2g + l*EE; const float* b2g = p.l2b + l*EE;
        const float* cacl = p.cac + (size_t)l*BB*EE;
        const float* b2bias = p.b2 + l*EE;
        float* yi = (blockIdx.x == 0) ? p.y : nullptr;
        const int c0 = ln*8;
        #pragma unroll 1
        for (int r = w*4; r < w*4 + 4; ++r){
          float v[8];
          #pragma unroll
          for (int j = 0; j < 4; ++j){
            float2 t2 = ld8(p.o2 + r*EE + c0 + 2*j); v[2*j] = t2.x; v[2*j+1] = t2.y;
          }
          float s = 0.f, s2 = 0.f;
          #pragma unroll
          for (int j = 0; j < 8; ++j){ s += v[j]; s2 += v[j]*v[j]; }
          s = wave_sum(s); s2 = wave_sum(s2);
          float m = s*(1.f/EE), inv = rsqrtf(s2*(1.f/EE) - m*m + 1e-5f);
          float4 ca0 = *(const float4*)(cacl + r*EE + c0);
          float4 ca1 = *(const float4*)(cacl + r*EE + c0 + 4);
          float n[8];
          n[0]=(v[0]-m)*inv*g1[c0+0]+b1g[c0+0]+ca0.x; n[1]=(v[1]-m)*inv*g1[c0+1]+b1g[c0+1]+ca0.y;
          n[2]=(v[2]-m)*inv*g1[c0+2]+b1g[c0+2]+ca0.z; n[3]=(v[3]-m)*inv*g1[c0+3]+b1g[c0+3]+ca0.w;
          n[4]=(v[4]-m)*inv*g1[c0+4]+b1g[c0+4]+ca1.x; n[5]=(v[5]-m)*inv*g1[c0+5]+b1g[c0+5]+ca1.y;
          n[6]=(v[6]-m)*inv*g1[c0+6]+b1g[c0+6]+ca1.z; n[7]=(v[7]-m)*inv*g1[c0+7]+b1g[c0+7]+ca1.w;
          float uu = 0.f, u2 = 0.f;
          #pragma unroll
          for (int j = 0; j < 8; ++j){ uu += n[j]; u2 += n[j]*n[j]; }
          uu = wave_sum(uu); u2 = wave_sum(u2);
          float m2 = uu*(1.f/EE), inv2 = rsqrtf(u2*(1.f/EE) - m2*m2 + 1e-5f);
          #pragma unroll
          for (int j = 0; j < 8; ++j) n[j] = (n[j]-m2)*inv2*g2[c0+j] + b2g[c0+j];
          if (yi){
            #pragma unroll
            for (int j = 0; j < 4; ++j)
              st8(yi + r*EE + c0 + 2*j, n[2*j]+b2bias[c0+2*j], n[2*j+1]+b2bias[c0+2*j+1]);
          }
          uint4 pk;
          pk.x = pk2(n[0],n[1]); pk.y = pk2(n[2],n[3]); pk.z = pk2(n[4],n[5]); pk.w = pk2(n[6],n[7]);
          *(uint4*)(xs + r*LDP + c0) = pk;
        }
        __syncthreads();
        const unsigned short* W1 = p.w1b + (size_t)l*FFD*EE;
        const float* bb1 = p.b1 + l*FFD;
        for (int u = w*G + blockIdx.x; u < 128; u += NW*G){
          int f0w = (u >> 2)*64 + (u & 3)*16;
          const unsigned short* ar = W1 + (size_t)(f0w+lm)*EE + kg*8;
          f32x4 a0 = {0,0,0,0}, a1 = {0,0,0,0};
          mmloop(16, ar, xs + lm*LDP + kg*8, xs + (lm+16)*LDP + kg*8, a0, a1);
          int f = f0w + kg*4;
          float g0[4], g1v[4];
          #pragma unroll
          for (int r = 0; r < 4; ++r){
            float v0 = a0[r] + bb1[f+r], v1 = a1[r] + bb1[f+r];
            g0[r] = 0.5f*v0*(1.f + erff(v0*0.70710678118654752f));
            g1v[r] = 0.5f*v1*(1.f + erff(v1*0.70710678118654752f));
          }
          st8u(&p.Hb[lm*FFD+f],      pk2(g0[0],g0[1]),  pk2(g0[2],g0[3]));
          st8u(&p.Hb[(lm+16)*FFD+f], pk2(g1v[0],g1v[1]), pk2(g1v[2],g1v[3]));
        }
      }
      bar();

      // ---- ffn2: y += H @ w2.T (k-split x4, atomics) ----
      {
        const unsigned short* W2 = p.w2b + (size_t)l*EE*FFD;
        for (int u = w*G + blockIdx.x; u < 128; u += NW*G){
          int tile = u >> 2, sub = u & 3;
          int f0w = (tile & 7)*64 + sub*16, k0 = (tile >> 3)*512;
          const unsigned short* ar = W2 + (size_t)(f0w+lm)*FFD + k0 + kg*8;
          f32x4 a0 = {0,0,0,0}, a1 = {0,0,0,0};
          #pragma unroll 2
          for (int ks = 0; ks < 16; ++ks){
            bf16x8 af = *reinterpret_cast<const bf16x8*>(ar + ks*32);
            BF8 b0, b1;
            const unsigned short* h0 = p.Hb + lm*FFD + k0 + ks*32 + kg*8;
            const unsigned short* h1 = p.Hb + (lm+16)*FFD + k0 + ks*32 + kg*8;
            b0.q[0] = ld8u(h0); b0.q[1] = ld8u(h0+4);
            b1.q[0] = ld8u(h1); b1.q[1] = ld8u(h1+4);
            a0 = mfma16(af, b0.v, a0);
            a1 = mfma16(af, b1.v, a1);
          }
          int f = f0w + kg*4;
          #pragma unroll
          for (int r = 0; r < 4; ++r){
            atomicAdd(&p.y[lm*EE + f + r], a0[r]);
            atomicAdd(&p.y[(lm+16)*EE + f + r], a1[r]);
          }
        }
      }
      bar();
    }

    // ---- logits = LN3(y) @ outw.T + outb ----
    {
      stage_x(xs, nullptr, p.y, p.l3g + 3*EE, p.l3b + 3*EE, 1, nullptr);
      for (int u = w*G + blockIdx.x; u < 512; u += NW*G){
        int f0w = (u >> 2)*64 + (u & 3)*16;
        const unsigned short* ar = p.outwb + (size_t)(f0w+lm)*EE + kg*8;
        f32x4 a0 = {0,0,0,0}, a1 = {0,0,0,0};
        mmloop(16, ar, xs + lm*LDP + kg*8, xs + (lm+16)*LDP + kg*8, a0, a1);
        int f = f0w + kg*4;
        st8(&p.logits[lm*VV+f],        a0[0]+p.outb[f],   a0[1]+p.outb[f+1]);
        st8(&p.logits[lm*VV+f+2],      a0[2]+p.outb[f+2], a0[3]+p.outb[f+3]);
        st8(&p.logits[(lm+16)*VV+f],   a1[0]+p.outb[f],   a1[1]+p.outb[f+1]);
        st8(&p.logits[(lm+16)*VV+f+2], a1[2]+p.outb[f+2], a1[3]+p.outb[f+3]);
      }
    }
    bar();

    // ---- dual softmax + sample (block b < 32 handles row b) ----
    if (blockIdx.x < BB){
      const int b = blockIdx.x;
      const float* lr = p.logits + (size_t)b*VV;
      const float* gr = p.gumb + (size_t)step*BB*VV + (size_t)b*VV;
      float lv[16], sv[16];
      float m1 = -1e30f, m2 = -1e30f;
      #pragma unroll
      for (int c = 0; c < 4; ++c){
        int i0 = t*4 + c*2048;
        float2 x0 = ld8(lr + i0), x1 = ld8(lr + i0 + 2);
        float4 gv = *(const float4*)(gr + i0);
        lv[c*4+0] = x0.x; lv[c*4+1] = x0.y; lv[c*4+2] = x1.x; lv[c*4+3] = x1.y;
        sv[c*4+0] = x0.x + gv.x; sv[c*4+1] = x0.y + gv.y;
        sv[c*4+2] = x1.x + gv.z; sv[c*4+3] = x1.y + gv.w;
        #pragma unroll
        for (int j = 0; j < 4; ++j){
          m1 = fmaxf(m1, lv[c*4+j]); m2 = fmaxf(m2, sv[c*4+j]);
        }
      }
      for (int o = 32; o; o >>= 1){ m1 = fmaxf(m1, __shfl_down(m1,o)); m2 = fmaxf(m2, __shfl_down(m2,o)); }
      if (ln == 0){ red[w] = m1; red[8+w] = m2; }
      __syncthreads();
      m1 = -1e30f; m2 = -1e30f;
      #pragma unroll
      for (int k = 0; k < 8; ++k){ m1 = fmaxf(m1, red[k]); m2 = fmaxf(m2, red[8+k]); }
      __syncthreads();
      float s1 = 0.f, s2 = 0.f;
      #pragma unroll
      for (int i = 0; i < 16; ++i){ s1 += __expf(lv[i]-m1); s2 += __expf(sv[i]-m2); }
      for (int o = 32; o; o >>= 1){ s1 += __shfl_down(s1,o); s2 += __shfl_down(s2,o); }
      if (ln == 0){ red[w] = s1; red[8+w] = s2; }
      __syncthreads();
      s1 = 0.f; s2 = 0.f;
      #pragma unroll
      for (int k = 0; k < 8; ++k){ s1 += red[k]; s2 += red[8+k]; }
      float r1 = 1.f/s1, r2 = 1.f/s2;
      float* dq = p.dseq + (size_t)b*((TT+1)*VV) + (size_t)step*VV;
      float* dd = p.ddist + (size_t)step*BB*VV + (size_t)b*VV;
      #pragma unroll
      for (int c = 0; c < 4; ++c){
        int i0 = t*4 + c*2048;
        float4 ddv, dqv;
        ddv.x = __expf(lv[c*4+0]-m1)*r1; ddv.y = __expf(lv[c*4+1]-m1)*r1;
        ddv.z = __expf(lv[c*4+2]-m1)*r1; ddv.w = __expf(lv[c*4+3]-m1)*r1;
        dqv.x = __expf(sv[c*4+0]-m2)*r2; dqv.y = __expf(sv[c*4+1]-m2)*r2;
        dqv.z = __expf(sv[c*4+2]-m2)*r2; dqv.w = __expf(sv[c*4+3]-m2)*r2;
        *(float4*)(dd + i0) = ddv;
        *(float4*)(dq + i0) = dqv;
        st8u(&p.sbf[(size_t)b*VV + i0], pk2(dqv.x,dqv.y), pk2(dqv.z,dqv.w));
      }
      if (t < 256) st8(&p.x[b*EE + 2*t], 0.f, 0.f);
    }
    bar();

    // ---- x += (sample @ emb) * sqrt(E) ----
    for (int u = w*G + blockIdx.x; u < 256; u += NW*G){
      int tile = u >> 2, sub = u & 3;
      int e0w = (tile & 7)*64 + sub*16, v0 = (tile >> 3)*1024;
      const unsigned short* ar = p.eTb + (size_t)(e0w+lm)*VV + v0 + kg*8;
      f32x4 a0 = {0,0,0,0}, a1 = {0,0,0,0};
      #pragma unroll 4
      for (int ks = 0; ks < 32; ++ks){
        bf16x8 af = *reinterpret_cast<const bf16x8*>(ar + ks*32);
        BF8 b0, b1;
        const unsigned short* s0 = p.sbf + (size_t)lm*VV + v0 + ks*32 + kg*8;
        const unsigned short* s1 = p.sbf + (size_t)(lm+16)*VV + v0 + ks*32 + kg*8;
        b0.q[0] = ld8u(s0); b0.q[1] = ld8u(s0+4);
        b1.q[0] = ld8u(s1); b1.q[1] = ld8u(s1+4);
        a0 = mfma16(af, b0.v, a0);
        a1 = mfma16(af, b1.v, a1);
      }
      int e = e0w + kg*4;
      #pragma unroll
      for (int r = 0; r < 4; ++r){
        atomicAdd(&p.x[lm*EE + e + r], a0[r]*SCALE_EMB);
        atomicAdd(&p.x[(lm+16)*EE + e + r], a1[r]*SCALE_EMB);
      }
    }
    bar();
  }
}

// ---------------- host ----------------
extern "C" void kernel_launch(void* const* d_in, const int* in_sizes, int n_in,
                              void* d_out, int out_size, void* d_ws, size_t ws_size,
                              hipStream_t stream){
  (void)in_sizes; (void)n_in; (void)out_size; (void)ws_size;
  const float* enc  = (const float*)d_in[0];
  const float* spec = (const float*)d_in[1];
  const float* embw = (const float*)d_in[2];
  const float* outw = (const float*)d_in[3];
  const float* outb = (const float*)d_in[4];
  const float* gumb = (const float*)d_in[5];
  const float* saqw = (const float*)d_in[6];
  const float* saqb = (const float*)d_in[7];
  const float* saow = (const float*)d_in[8];
  const float* saob = (const float*)d_in[9];
  const float* caqw = (const float*)d_in[10];
  const float* caqb = (const float*)d_in[11];
  const float* caow = (const float*)d_in[12];
  const float* caob = (const float*)d_in[13];

  unsigned char* wp = (unsigned char*)d_ws;
  auto alloc = [&](size_t bytes) -> void* {
    void* r = (void*)wp; wp += (bytes + 255) & ~(size_t)255; return r;
  };
  float* x      = (float*)alloc(BB*EE*4);
  float* y      = (float*)alloc(BB*EE*4);
  float* q      = (float*)alloc(BB*EE*4);
  float* xln    = (float*)alloc(BB*EE*4);
  float* o2     = (float*)alloc(BB*EE*4);
  float* of     = (float*)alloc(BB*EE*4);
  float* logits = (float*)alloc((size_t)BB*VV*4);
  float* venc   = (float*)alloc((size_t)LL*BB*EE*4);
  float* cac    = (float*)alloc((size_t)LL*BB*EE*4);
  float* kc     = (float*)alloc((size_t)LL*BB*EE*TT*4);
  float* vc     = (float*)alloc((size_t)LL*BB*EE*TT*4);
  unsigned short* Hb    = (unsigned short*)alloc(BB*FFD*2);
  unsigned short* sbf   = (unsigned short*)alloc((size_t)BB*VV*2);
  unsigned short* wqkvb = (unsigned short*)alloc((size_t)LL*3*EE*EE*2);
  unsigned short* owb   = (unsigned short*)alloc((size_t)LL*EE*EE*2);
  unsigned short* w1b   = (unsigned short*)alloc((size_t)LL*FFD*EE*2);
  unsigned short* w2b   = (unsigned short*)alloc((size_t)LL*FFD*EE*2);
  unsigned short* outwb = (unsigned short*)alloc((size_t)VV*EE*2);
  unsigned short* eTb   = (unsigned short*)alloc((size_t)EE*VV*2);
  unsigned short* cavwb = (unsigned short*)alloc((size_t)LL*EE*EE*2);
  unsigned short* caowb = (unsigned short*)alloc((size_t)LL*EE*EE*2);
  unsigned* cnt = (unsigned*)alloc(256);

  PrepParams pp;
  pp.spec = spec; pp.embw = embw; pp.outwf = outw; pp.saqw = saqw; pp.saow = saow;
  pp.caqw = caqw; pp.caow = caow; pp.w1f = (const float*)d_in[20]; pp.w2f = (const float*)d_in[22];
  pp.dseq = (float*)d_out; pp.x = x;
  pp.wqkvb = wqkvb; pp.owb = owb; pp.w1b = w1b; pp.w2b = w2b; pp.outwb = outwb;
  pp.cavwb = cavwb; pp.caowb = caowb; pp.eTb = eTb;

  MegaParams p;
  p.enc = enc; p.gumb = gumb; p.outb = outb;
  p.saqb = saqb; p.saob = saob; p.caqb = caqb; p.caob = caob;
  p.l1g = (const float*)d_in[14]; p.l1b = (const float*)d_in[15];
  p.l2g = (const float*)d_in[16]; p.l2b = (const float*)d_in[17];
  p.l3g = (const float*)d_in[18]; p.l3b = (const float*)d_in[19];
  p.b1  = (const float*)d_in[21]; p.b2  = (const float*)d_in[23];
  p.dseq = (float*)d_out;
  p.ddist = (float*)d_out + (size_t)BB*(TT+1)*VV;
  p.x = x; p.y = y; p.q = q; p.xln = xln; p.o2 = o2; p.of = of;
  p.logits = logits; p.venc = venc; p.cac = cac; p.kc = kc; p.vc = vc;
  p.Hb = Hb; p.sbf = sbf;
  p.wqkvb = wqkvb; p.owb = owb; p.w1b = w1b; p.w2b = w2b; p.outwb = outwb;
  p.eTb = eTb; p.cavwb = cavwb; p.caowb = caowb;
  p.cnt = cnt;

  hipMemsetAsync((void*)cnt, 0, 256, stream);
  k_prep<<<768, 256, 0, stream>>>(pp);
  mega<<<G, BLK, 0, stream>>>(p);
}